// Round 1
// baseline (575.315 us; speedup 1.0000x reference)
//
#include <hip/hip_runtime.h>

// Attention_72275709657473 — full MHA block on gfx950.
// Pipeline: cast(fp32->bf16) -> QKV proj GEMM (bf16 MFMA) -> causal flash attn -> out proj.
// ws layout (bytes): Xq/Xk/Xv bf16 (3x16MB) | Wq/Wk/Wv/Wo bf16 (4x2MB) | Q/K/V bf16 (3x16MB).
// Og (attn output, bf16) reuses the Xq region (dead after QKV GEMM). Total ~104MB.

#define E 1024
#define HEADS 16
#define HD 64
#define SEQ 2048
#define BATCH 4
#define MROWS (BATCH * SEQ) /* 8192 */

typedef __bf16 bf16x8 __attribute__((ext_vector_type(8)));
typedef float f32x4 __attribute__((ext_vector_type(4)));
typedef unsigned short ushort8v __attribute__((ext_vector_type(8)));

typedef __attribute__((address_space(1))) void gvoid;
typedef __attribute__((address_space(3))) void lvoid;

__device__ __forceinline__ void async16(const void* g, void* l) {
  __builtin_amdgcn_global_load_lds((gvoid*)g, (lvoid*)l, 16, 0, 0);
}

__device__ __forceinline__ unsigned short f2bf(float f) {
  union { float f; unsigned int u; } v;
  v.f = f;
  unsigned int r = v.u + 0x7FFFu + ((v.u >> 16) & 1u); // round-to-nearest-even
  return (unsigned short)(r >> 16);
}

__device__ __forceinline__ void store_out(unsigned short* p, float v) { *p = f2bf(v); }
__device__ __forceinline__ void store_out(float* p, float v) { *p = v; }

// ---------------- cast kernels ----------------
struct CastArgs {
  const float* src[4];
  unsigned short* dst[4];
  int n;
};

__global__ __launch_bounds__(256) void cast_kernel(CastArgs a) {
  const float* s = a.src[blockIdx.z];
  unsigned short* d = a.dst[blockIdx.z];
  const int n = a.n;
  const int stride = gridDim.x * blockDim.x * 4;
  for (int i = (blockIdx.x * blockDim.x + threadIdx.x) * 4; i < n; i += stride) {
    float4 v = *(const float4*)(s + i);
    ushort4 o;
    o.x = f2bf(v.x); o.y = f2bf(v.y); o.z = f2bf(v.z); o.w = f2bf(v.w);
    *(ushort4*)(d + i) = o;
  }
}

// ---------------- GEMM: C[M,N] = A[M,K] @ W[N,K]^T, epilogue (acc+bias)*scale ----------------
// 128x128 tile, BK=64, 256 threads = 4 waves in 2x2, each wave 64x64 (4x4 of 16x16x32 MFMA).
// LDS tiles stored row-major 128x64 bf16 with XOR chunk swizzle: chunk c of row r at slot c^(r&7).
template <typename OutT>
__device__ __forceinline__ void gemm_body(const unsigned short* __restrict__ A,
                                          const unsigned short* __restrict__ W,
                                          const float* __restrict__ bias,
                                          OutT* __restrict__ out, float scale) {
  __shared__ unsigned short At[128 * 64];
  __shared__ unsigned short Wt[128 * 64];
  const int tid = threadIdx.x;
  const int lane = tid & 63;
  const int wv = tid >> 6;
  const int wm = wv & 1, wn = wv >> 1;
  const int li = lane & 15, g = lane >> 4;
  const int m0 = blockIdx.x * 128, n0 = blockIdx.y * 128;
  f32x4 acc[4][4] = {};

  for (int k0 = 0; k0 < E; k0 += 64) {
    __syncthreads();
#pragma unroll
    for (int i = 0; i < 4; ++i) {
      int c = tid + 256 * i;
      int row = c >> 3, slot = c & 7;
      int gc = slot ^ (row & 7);
      async16(A + (size_t)(m0 + row) * E + k0 + gc * 8, &At[c * 8]);
      async16(W + (size_t)(n0 + row) * E + k0 + gc * 8, &Wt[c * 8]);
    }
    asm volatile("s_waitcnt vmcnt(0)" ::: "memory");
    __syncthreads();
#pragma unroll
    for (int kk = 0; kk < 2; ++kk) {
      bf16x8 af[4], bfr[4];
#pragma unroll
      for (int mt = 0; mt < 4; ++mt) {
        int r = wm * 64 + mt * 16 + li;
        int slot = (kk * 4 + g) ^ (r & 7);
        af[mt] = *(const bf16x8*)&At[r * 64 + slot * 8];
      }
#pragma unroll
      for (int nt = 0; nt < 4; ++nt) {
        int r = wn * 64 + nt * 16 + li;
        int slot = (kk * 4 + g) ^ (r & 7);
        bfr[nt] = *(const bf16x8*)&Wt[r * 64 + slot * 8];
      }
#pragma unroll
      for (int mt = 0; mt < 4; ++mt)
#pragma unroll
        for (int nt = 0; nt < 4; ++nt)
          acc[mt][nt] =
              __builtin_amdgcn_mfma_f32_16x16x32_bf16(af[mt], bfr[nt], acc[mt][nt], 0, 0, 0);
    }
  }

#pragma unroll
  for (int nt = 0; nt < 4; ++nt) {
    int col = n0 + wn * 64 + nt * 16 + li;
    float bv = bias[col];
#pragma unroll
    for (int mt = 0; mt < 4; ++mt) {
#pragma unroll
      for (int r = 0; r < 4; ++r) {
        int row = m0 + wm * 64 + mt * 16 + g * 4 + r;
        store_out(&out[(size_t)row * E + col], (acc[mt][nt][r] + bv) * scale);
      }
    }
  }
}

struct QkvArgs {
  const unsigned short* A[3];
  const unsigned short* W[3];
  const float* bias[3];
  unsigned short* out[3];
  float scale[3];
};

__global__ __launch_bounds__(256) void gemm_qkv(QkvArgs p) {
  const int z = blockIdx.z;
  gemm_body<unsigned short>(p.A[z], p.W[z], p.bias[z], p.out[z], p.scale[z]);
}

__global__ __launch_bounds__(256) void gemm_out_k(const unsigned short* __restrict__ A,
                                                  const unsigned short* __restrict__ W,
                                                  const float* __restrict__ bias,
                                                  float* __restrict__ out) {
  gemm_body<float>(A, W, bias, out, 1.0f);
}

// ---------------- causal flash attention ----------------
// grid (16 qtiles, 64 b*h), 256 threads = 4 waves; wave w owns Q rows [s0+32w, s0+32w+32).
// Q fragments in registers; K in LDS (row-major, swizzled); V in LDS transposed Vt[d][key]
// (chunk c of row d at slot c^(d&15)); P per-wave-private LDS strip 32x128 (slot c^(row&15)).
__global__ __launch_bounds__(256) void flash_kernel(const unsigned short* __restrict__ Qb,
                                                    const unsigned short* __restrict__ Kb,
                                                    const unsigned short* __restrict__ Vb,
                                                    unsigned short* __restrict__ Ob) {
  __shared__ unsigned short Kt[128 * 64];
  __shared__ unsigned short Vt[64 * 128];
  __shared__ unsigned short Pt[4][32 * 128];
  const int qt = blockIdx.x, bh = blockIdx.y;
  const int b = bh >> 4, h = bh & 15;
  const size_t base = (size_t)b * SEQ * E + (size_t)h * HD;
  const unsigned short* Qp = Qb + base;
  const unsigned short* Kp = Kb + base;
  const unsigned short* Vp = Vb + base;
  const int tid = threadIdx.x, lane = tid & 63, wv = tid >> 6;
  const int li = lane & 15, g = lane >> 4;
  const int s0 = qt * 128;

  // Q fragments (A-layout): row = lane&15, k = (lane>>4)*8 contiguous in d
  bf16x8 qf[2][2];
#pragma unroll
  for (int mt = 0; mt < 2; ++mt)
#pragma unroll
    for (int kk = 0; kk < 2; ++kk) {
      int row = s0 + wv * 32 + mt * 16 + li;
      qf[mt][kk] = *(const bf16x8*)(Qp + (size_t)row * E + kk * 32 + g * 8);
    }

  f32x4 oacc[2][4] = {};
  float mi[2][4], lsum[2][4];
#pragma unroll
  for (int mt = 0; mt < 2; ++mt)
#pragma unroll
    for (int r = 0; r < 4; ++r) { mi[mt][r] = -1e30f; lsum[mt][r] = 0.0f; }

  for (int j = 0; j <= qt; ++j) {
    __syncthreads();
    // stage K tile [128 keys x 64 d] via async copy, swizzled
#pragma unroll
    for (int i = 0; i < 4; ++i) {
      int c = tid + 256 * i;
      int row = c >> 3, slot = c & 7;
      int gc = slot ^ (row & 7);
      async16(Kp + (size_t)(j * 128 + row) * E + gc * 8, &Kt[c * 8]);
    }
    // stage V transposed: Vt[d][key], swizzled (chunk of 8 keys at slot (key>>3)^(d&15))
#pragma unroll
    for (int i = 0; i < 4; ++i) {
      int c = tid + 256 * i;
      int key = c & 127, db = (c >> 7) * 8;
      ushort8v vv = *(const ushort8v*)(Vp + (size_t)(j * 128 + key) * E + db);
#pragma unroll
      for (int jj = 0; jj < 8; ++jj) {
        int n = db + jj;
        int slot = (key >> 3) ^ (n & 15);
        Vt[n * 128 + slot * 8 + (key & 7)] = vv[jj];
      }
    }
    asm volatile("s_waitcnt vmcnt(0)" ::: "memory");
    __syncthreads();

    // S = Q K^T : per-wave 32x128 strip
    f32x4 sacc[2][8] = {};
#pragma unroll
    for (int kk = 0; kk < 2; ++kk) {
      bf16x8 kf[8];
#pragma unroll
      for (int nt = 0; nt < 8; ++nt) {
        int key = nt * 16 + li;
        int slot = (kk * 4 + g) ^ (key & 7);
        kf[nt] = *(const bf16x8*)&Kt[key * 64 + slot * 8];
      }
#pragma unroll
      for (int mt = 0; mt < 2; ++mt)
#pragma unroll
        for (int nt = 0; nt < 8; ++nt)
          sacc[mt][nt] =
              __builtin_amdgcn_mfma_f32_16x16x32_bf16(qf[mt][kk], kf[nt], sacc[mt][nt], 0, 0, 0);
    }

    if (j == qt) { // diagonal tile: mask col > row (tile-local indices, same tile offset)
#pragma unroll
      for (int mt = 0; mt < 2; ++mt)
#pragma unroll
        for (int nt = 0; nt < 8; ++nt)
#pragma unroll
          for (int r = 0; r < 4; ++r) {
            int colg = nt * 16 + li;
            int rowg = wv * 32 + mt * 16 + g * 4 + r;
            if (colg > rowg) sacc[mt][nt][r] = -1e30f;
          }
    }

    // online softmax; C-layout row = (lane>>4)*4+reg -> row stats reduce across lane&15
    float alpha[2][4];
#pragma unroll
    for (int mt = 0; mt < 2; ++mt)
#pragma unroll
      for (int r = 0; r < 4; ++r) {
        float mx = sacc[mt][0][r];
#pragma unroll
        for (int nt = 1; nt < 8; ++nt) mx = fmaxf(mx, sacc[mt][nt][r]);
        mx = fmaxf(mx, __shfl_xor(mx, 1));
        mx = fmaxf(mx, __shfl_xor(mx, 2));
        mx = fmaxf(mx, __shfl_xor(mx, 4));
        mx = fmaxf(mx, __shfl_xor(mx, 8));
        float mnew = fmaxf(mi[mt][r], mx);
        alpha[mt][r] = __expf(mi[mt][r] - mnew);
        mi[mt][r] = mnew;
      }

    unsigned short* Pw = &Pt[wv][0];
#pragma unroll
    for (int mt = 0; mt < 2; ++mt) {
      float rsum[4] = {0.f, 0.f, 0.f, 0.f};
#pragma unroll
      for (int nt = 0; nt < 8; ++nt)
#pragma unroll
        for (int r = 0; r < 4; ++r) {
          float p = __expf(sacc[mt][nt][r] - mi[mt][r]);
          rsum[r] += p;
          int row = mt * 16 + g * 4 + r;
          int col = nt * 16 + li;
          int slot = (col >> 3) ^ (row & 15);
          Pw[row * 128 + slot * 8 + (col & 7)] = f2bf(p);
        }
#pragma unroll
      for (int r = 0; r < 4; ++r) {
        float s = rsum[r];
        s += __shfl_xor(s, 1);
        s += __shfl_xor(s, 2);
        s += __shfl_xor(s, 4);
        s += __shfl_xor(s, 8);
        lsum[mt][r] = lsum[mt][r] * alpha[mt][r] + s;
#pragma unroll
        for (int dt = 0; dt < 4; ++dt) oacc[mt][dt][r] *= alpha[mt][r];
      }
    }
    asm volatile("s_waitcnt lgkmcnt(0)" ::: "memory"); // P writes -> own-wave reads

    // O += P V  (A = P from LDS, B = V^T rows from Vt)
#pragma unroll
    for (int kk = 0; kk < 4; ++kk) {
      bf16x8 pf[2], vf[4];
#pragma unroll
      for (int mt = 0; mt < 2; ++mt) {
        int m = mt * 16 + li;
        int slot = (kk * 4 + g) ^ (m & 15);
        pf[mt] = *(const bf16x8*)&Pw[m * 128 + slot * 8];
      }
#pragma unroll
      for (int dt = 0; dt < 4; ++dt) {
        int n = dt * 16 + li;
        int slot = (kk * 4 + g) ^ (n & 15);
        vf[dt] = *(const bf16x8*)&Vt[n * 128 + slot * 8];
      }
#pragma unroll
      for (int mt = 0; mt < 2; ++mt)
#pragma unroll
        for (int dt = 0; dt < 4; ++dt)
          oacc[mt][dt] =
              __builtin_amdgcn_mfma_f32_16x16x32_bf16(pf[mt], vf[dt], oacc[mt][dt], 0, 0, 0);
    }
  }

  unsigned short* Op = Ob + base;
#pragma unroll
  for (int mt = 0; mt < 2; ++mt)
#pragma unroll
    for (int dt = 0; dt < 4; ++dt)
#pragma unroll
      for (int r = 0; r < 4; ++r) {
        int row = s0 + wv * 32 + mt * 16 + g * 4 + r;
        int col = dt * 16 + li;
        Op[(size_t)row * E + col] = f2bf(oacc[mt][dt][r] / lsum[mt][r]);
      }
}

// ---------------- launch ----------------
extern "C" void kernel_launch(void* const* d_in, const int* in_sizes, int n_in,
                              void* d_out, int out_size, void* d_ws, size_t ws_size,
                              hipStream_t stream) {
  const float* q  = (const float*)d_in[0];
  const float* k  = (const float*)d_in[1];
  const float* v  = (const float*)d_in[2];
  const float* Wq = (const float*)d_in[3];
  const float* bq = (const float*)d_in[4];
  const float* Wk = (const float*)d_in[5];
  const float* bk = (const float*)d_in[6];
  const float* Wv = (const float*)d_in[7];
  const float* bv = (const float*)d_in[8];
  const float* Wo = (const float*)d_in[9];
  const float* bo = (const float*)d_in[10];

  unsigned short* Xq  = (unsigned short*)d_ws;
  unsigned short* Xk  = Xq + (size_t)MROWS * E;
  unsigned short* Xv  = Xk + (size_t)MROWS * E;
  unsigned short* Wqb = Xv + (size_t)MROWS * E;
  unsigned short* Wkb = Wqb + (size_t)E * E;
  unsigned short* Wvb = Wkb + (size_t)E * E;
  unsigned short* Wob = Wvb + (size_t)E * E;
  unsigned short* Qb  = Wob + (size_t)E * E;
  unsigned short* Kb  = Qb + (size_t)MROWS * E;
  unsigned short* Vb  = Kb + (size_t)MROWS * E;
  unsigned short* Og  = Xq; // Xq region is dead after the QKV GEMM

  CastArgs ca;
  ca.src[0] = q; ca.src[1] = k; ca.src[2] = v; ca.src[3] = nullptr;
  ca.dst[0] = Xq; ca.dst[1] = Xk; ca.dst[2] = Xv; ca.dst[3] = nullptr;
  ca.n = MROWS * E;
  cast_kernel<<<dim3(1024, 1, 3), 256, 0, stream>>>(ca);

  CastArgs cw;
  cw.src[0] = Wq; cw.src[1] = Wk; cw.src[2] = Wv; cw.src[3] = Wo;
  cw.dst[0] = Wqb; cw.dst[1] = Wkb; cw.dst[2] = Wvb; cw.dst[3] = Wob;
  cw.n = E * E;
  cast_kernel<<<dim3(256, 1, 4), 256, 0, stream>>>(cw);

  QkvArgs p;
  p.A[0] = Xq;  p.A[1] = Xk;  p.A[2] = Xv;
  p.W[0] = Wqb; p.W[1] = Wkb; p.W[2] = Wvb;
  p.bias[0] = bq; p.bias[1] = bk; p.bias[2] = bv;
  p.out[0] = Qb; p.out[1] = Kb; p.out[2] = Vb;
  p.scale[0] = 0.125f; p.scale[1] = 1.0f; p.scale[2] = 1.0f; // SCALE = 64^-0.5 folded into Q
  gemm_qkv<<<dim3(64, 8, 3), 256, 0, stream>>>(p);

  flash_kernel<<<dim3(16, 64), 256, 0, stream>>>(Qb, Kb, Vb, Og);

  gemm_out_k<<<dim3(64, 8), 256, 0, stream>>>(Og, Wob, bo, (float*)d_out);
}

// Round 3
// 407.581 us; speedup vs baseline: 1.4115x; 1.4115x over previous
//
#include <hip/hip_runtime.h>

// Attention_72275709657473 — full MHA block on gfx950.
// Pipeline: cast(fp32->bf16) -> QKV proj GEMM (bf16 MFMA) -> causal flash attn -> out proj.
// Flash uses the TRANSPOSED formulation: S^T = K Q^T, O^T = V^T P^T, so the
// P (C-layout) -> PV B-fragment transform is done with in-wave shuffles (no P LDS).
// The 128-key tile is processed as two 64-key chunks to keep VGPR pressure ~156
// (fits __launch_bounds__(256,3) cap of ~170 without spilling).
// ws layout: Xq/Xk/Xv bf16 (3x16MB) | Wq/Wk/Wv/Wo bf16 (4x2MB) | Q/K/V bf16 (3x16MB).
// Og (attn output, bf16) reuses the Xq region. Total ~104MB.

#define E 1024
#define HEADS 16
#define HD 64
#define SEQ 2048
#define BATCH 4
#define MROWS (BATCH * SEQ) /* 8192 */

typedef __bf16 bf16x8 __attribute__((ext_vector_type(8)));
typedef __bf16 bf16x2 __attribute__((ext_vector_type(2)));
typedef float f32x4 __attribute__((ext_vector_type(4)));
typedef unsigned short ushort8v __attribute__((ext_vector_type(8)));

typedef __attribute__((address_space(1))) void gvoid;
typedef __attribute__((address_space(3))) void lvoid;

__device__ __forceinline__ void async16(const void* g, void* l) {
  __builtin_amdgcn_global_load_lds((gvoid*)g, (lvoid*)l, 16, 0, 0);
}

__device__ __forceinline__ unsigned short f2bf(float f) {
  union { float f; unsigned int u; } v;
  v.f = f;
  unsigned int r = v.u + 0x7FFFu + ((v.u >> 16) & 1u); // round-to-nearest-even
  return (unsigned short)(r >> 16);
}

__device__ __forceinline__ unsigned packbf(float a, float b) {
  bf16x2 t;
  t[0] = (__bf16)a;
  t[1] = (__bf16)b;
  return __builtin_bit_cast(unsigned, t);
}

__device__ __forceinline__ void store_out(unsigned short* p, float v) { *p = f2bf(v); }
__device__ __forceinline__ void store_out(float* p, float v) { *p = v; }

// ---------------- cast kernels ----------------
struct CastArgs {
  const float* src[4];
  unsigned short* dst[4];
  int n;
};

__global__ __launch_bounds__(256) void cast_kernel(CastArgs a) {
  const float* s = a.src[blockIdx.z];
  unsigned short* d = a.dst[blockIdx.z];
  const int n = a.n;
  const int stride = gridDim.x * blockDim.x * 4;
  for (int i = (blockIdx.x * blockDim.x + threadIdx.x) * 4; i < n; i += stride) {
    float4 v = *(const float4*)(s + i);
    ushort4 o;
    o.x = f2bf(v.x); o.y = f2bf(v.y); o.z = f2bf(v.z); o.w = f2bf(v.w);
    *(ushort4*)(d + i) = o;
  }
}

// ---------------- GEMM: C[M,N] = A[M,K] @ W[N,K]^T, epilogue (acc+bias)*scale ----------------
// 128x128 tile, BK=64, 256 threads = 4 waves in 2x2, each wave 64x64 (4x4 of 16x16x32 MFMA).
// LDS tiles row-major 128x64 bf16, XOR chunk swizzle: chunk c of row r at slot c^(r&7).
template <typename OutT>
__device__ __forceinline__ void gemm_body(const unsigned short* __restrict__ A,
                                          const unsigned short* __restrict__ W,
                                          const float* __restrict__ bias,
                                          OutT* __restrict__ out, float scale) {
  __shared__ unsigned short At[128 * 64];
  __shared__ unsigned short Wt[128 * 64];
  const int tid = threadIdx.x;
  const int lane = tid & 63;
  const int wv = tid >> 6;
  const int wm = wv & 1, wn = wv >> 1;
  const int li = lane & 15, g = lane >> 4;
  const int m0 = blockIdx.x * 128, n0 = blockIdx.y * 128;
  f32x4 acc[4][4] = {};

  for (int k0 = 0; k0 < E; k0 += 64) {
    __syncthreads();
#pragma unroll
    for (int i = 0; i < 4; ++i) {
      int c = tid + 256 * i;
      int row = c >> 3, slot = c & 7;
      int gc = slot ^ (row & 7);
      async16(A + (size_t)(m0 + row) * E + k0 + gc * 8, &At[c * 8]);
      async16(W + (size_t)(n0 + row) * E + k0 + gc * 8, &Wt[c * 8]);
    }
    asm volatile("s_waitcnt vmcnt(0)" ::: "memory");
    __syncthreads();
#pragma unroll
    for (int kk = 0; kk < 2; ++kk) {
      bf16x8 af[4], bfr[4];
#pragma unroll
      for (int mt = 0; mt < 4; ++mt) {
        int r = wm * 64 + mt * 16 + li;
        int slot = (kk * 4 + g) ^ (r & 7);
        af[mt] = *(const bf16x8*)&At[r * 64 + slot * 8];
      }
#pragma unroll
      for (int nt = 0; nt < 4; ++nt) {
        int r = wn * 64 + nt * 16 + li;
        int slot = (kk * 4 + g) ^ (r & 7);
        bfr[nt] = *(const bf16x8*)&Wt[r * 64 + slot * 8];
      }
#pragma unroll
      for (int mt = 0; mt < 4; ++mt)
#pragma unroll
        for (int nt = 0; nt < 4; ++nt)
          acc[mt][nt] =
              __builtin_amdgcn_mfma_f32_16x16x32_bf16(af[mt], bfr[nt], acc[mt][nt], 0, 0, 0);
    }
  }

#pragma unroll
  for (int nt = 0; nt < 4; ++nt) {
    int col = n0 + wn * 64 + nt * 16 + li;
    float bv = bias[col];
#pragma unroll
    for (int mt = 0; mt < 4; ++mt) {
#pragma unroll
      for (int r = 0; r < 4; ++r) {
        int row = m0 + wm * 64 + mt * 16 + g * 4 + r;
        store_out(&out[(size_t)row * E + col], (acc[mt][nt][r] + bv) * scale);
      }
    }
  }
}

struct QkvArgs {
  const unsigned short* A[3];
  const unsigned short* W[3];
  const float* bias[3];
  unsigned short* out[3];
  float scale[3];
};

__global__ __launch_bounds__(256) void gemm_qkv(QkvArgs p) {
  const int z = blockIdx.z;
  gemm_body<unsigned short>(p.A[z], p.W[z], p.bias[z], p.out[z], p.scale[z]);
}

__global__ __launch_bounds__(256) void gemm_out_k(const unsigned short* __restrict__ A,
                                                  const unsigned short* __restrict__ W,
                                                  const float* __restrict__ bias,
                                                  float* __restrict__ out) {
  gemm_body<float>(A, W, bias, out, 1.0f);
}

// ---------------- causal flash attention (transposed, 64-key chunks) ----------------
// grid (16 qtiles reversed, 64 b*h), 256 threads = 4 waves; wave w owns Q rows
// [s0+32w, s0+32w+32). Per 128-key j-tile, two 64-key chunks h:
//   S^T[key][q] = mfma(A=K-frag, B=Q-frag)   (C-layout: col=q=li, row=key=g*4+r)
//   online softmax per q: in-lane over 4 key-tiles x 4 regs, then shfl_xor 16/32
//   P^T -> PV B-fragment via in-wave shuffles (8 shfl + 4 sel per 16x16 tile)
//   O^T[d][q] += mfma(A=V^T-frag from Vt, B=P-frag)
// LDS: Kt 16KB + Vt 16KB = 32KB, no P buffer. VGPR working set ~156.
__global__ __launch_bounds__(256, 3) void flash_kernel(const unsigned short* __restrict__ Qb,
                                                       const unsigned short* __restrict__ Kb,
                                                       const unsigned short* __restrict__ Vb,
                                                       unsigned short* __restrict__ Ob) {
  __shared__ unsigned short Kt[128 * 64];
  __shared__ unsigned short Vt[64 * 128];
  const int qt = 15 - blockIdx.x; // long blocks first
  const int bh = blockIdx.y;
  const int b = bh >> 4, h16 = bh & 15;
  const size_t base = (size_t)b * SEQ * E + (size_t)h16 * HD;
  const unsigned short* Qp = Qb + base;
  const unsigned short* Kp = Kb + base;
  const unsigned short* Vp = Vb + base;
  unsigned short* Op = Ob + base;
  const int tid = threadIdx.x, lane = tid & 63, wv = tid >> 6;
  const int li = lane & 15, g = lane >> 4;
  const int s0 = qt * 128;
  const int slo = ((g & 1) << 5) | li; // source lane for P shuffles (lo half)

  // Q fragments (B-operand layout): lane holds Q[q = li][d = kk*32 + g*8 .. +7]
  bf16x8 qf[2][2];
#pragma unroll
  for (int mt = 0; mt < 2; ++mt)
#pragma unroll
    for (int kk = 0; kk < 2; ++kk) {
      int row = s0 + wv * 32 + mt * 16 + li;
      qf[mt][kk] = *(const bf16x8*)(Qp + (size_t)row * E + kk * 32 + g * 8);
    }

  f32x4 oacc[4][2] = {}; // [d-tile][q-tile], C-layout of O^T: col=q=li, row=d=g*4+r
  float mi[2] = {-1e30f, -1e30f};
  float lsum[2] = {0.0f, 0.0f};

  for (int j = 0; j <= qt; ++j) {
    __syncthreads();
    // stage K tile [128 keys x 64 d], swizzled (chunk c at slot c^(key&7))
#pragma unroll
    for (int i = 0; i < 4; ++i) {
      int c = tid + 256 * i;
      int row = c >> 3, slot = c & 7;
      int gc = slot ^ (row & 7);
      async16(Kp + (size_t)(j * 128 + row) * E + gc * 8, &Kt[c * 8]);
    }
    // stage V transposed: Vt[d][key], chunk (key>>3) of row d at slot (key>>3)^(d&15)
#pragma unroll
    for (int i = 0; i < 4; ++i) {
      int c = tid + 256 * i;
      int key = c & 127, db = (c >> 7) * 8;
      ushort8v vv = *(const ushort8v*)(Vp + (size_t)(j * 128 + key) * E + db);
#pragma unroll
      for (int jj = 0; jj < 8; ++jj) {
        int n = db + jj;
        int slot = (key >> 3) ^ (n & 15);
        Vt[n * 128 + slot * 8 + (key & 7)] = vv[jj];
      }
    }
    asm volatile("s_waitcnt vmcnt(0)" ::: "memory");
    __syncthreads();

#pragma unroll
    for (int h = 0; h < 2; ++h) {
      // wave-uniform skip: chunk entirely above the diagonal for this wave's rows
      if (j == qt && h * 64 > wv * 32 + 31) continue;

      // S^T = K Q^T for 64 keys: 4 key-tiles x 2 q-tiles
      f32x4 sacc[4][2] = {};
#pragma unroll
      for (int kk = 0; kk < 2; ++kk) {
        bf16x8 kf[4];
#pragma unroll
        for (int nt = 0; nt < 4; ++nt) {
          int key = h * 64 + nt * 16 + li;
          int slot = (kk * 4 + g) ^ (key & 7);
          kf[nt] = *(const bf16x8*)&Kt[key * 64 + slot * 8];
        }
#pragma unroll
        for (int nt = 0; nt < 4; ++nt)
#pragma unroll
          for (int mt = 0; mt < 2; ++mt)
            sacc[nt][mt] =
                __builtin_amdgcn_mfma_f32_16x16x32_bf16(kf[nt], qf[mt][kk], sacc[nt][mt], 0, 0, 0);
      }

      if (j == qt && h * 64 + 63 > wv * 32) { // chunk overlaps diagonal: mask key > q
#pragma unroll
        for (int nt = 0; nt < 4; ++nt)
#pragma unroll
          for (int mt = 0; mt < 2; ++mt)
#pragma unroll
            for (int r = 0; r < 4; ++r) {
              int keyg = h * 64 + nt * 16 + g * 4 + r;
              int qg = wv * 32 + mt * 16 + li;
              sacc[nt][mt][r] = (keyg > qg) ? -1e30f : sacc[nt][mt][r];
            }
      }

      // online softmax per q (C-layout col): in-lane 16 keys, then shfl_xor 16/32
      float alpha[2];
#pragma unroll
      for (int mt = 0; mt < 2; ++mt) {
        float mx = sacc[0][mt][0];
#pragma unroll
        for (int nt = 0; nt < 4; ++nt)
#pragma unroll
          for (int r = 0; r < 4; ++r) mx = fmaxf(mx, sacc[nt][mt][r]);
        mx = fmaxf(mx, __shfl_xor(mx, 16));
        mx = fmaxf(mx, __shfl_xor(mx, 32));
        float mnew = fmaxf(mi[mt], mx);
        alpha[mt] = __expf(mi[mt] - mnew);
        mi[mt] = mnew;
      }

      unsigned pk[4][2][2]; // packed bf16 P^T: [key-tile][q-tile][reg-pair]
      float rs[2] = {0.0f, 0.0f};
#pragma unroll
      for (int nt = 0; nt < 4; ++nt)
#pragma unroll
        for (int mt = 0; mt < 2; ++mt) {
          float p0 = __expf(sacc[nt][mt][0] - mi[mt]);
          float p1 = __expf(sacc[nt][mt][1] - mi[mt]);
          float p2 = __expf(sacc[nt][mt][2] - mi[mt]);
          float p3 = __expf(sacc[nt][mt][3] - mi[mt]);
          rs[mt] += (p0 + p1) + (p2 + p3);
          pk[nt][mt][0] = packbf(p0, p1);
          pk[nt][mt][1] = packbf(p2, p3);
        }
#pragma unroll
      for (int mt = 0; mt < 2; ++mt) {
        float s = rs[mt];
        s += __shfl_xor(s, 16);
        s += __shfl_xor(s, 32);
        lsum[mt] = lsum[mt] * alpha[mt] + s;
#pragma unroll
        for (int dt = 0; dt < 4; ++dt) oacc[dt][mt] *= alpha[mt];
      }

      // O^T += V^T P^T over 2 chunks of 32 keys
#pragma unroll
      for (int kk2 = 0; kk2 < 2; ++kk2) {
        const int kc = h * 2 + kk2; // 32-key chunk index within the 128-key tile
        bf16x8 vf[4];
#pragma unroll
        for (int dt = 0; dt < 4; ++dt) {
          int d = dt * 16 + li;
          int slot = (kc * 4 + g) ^ (d & 15);
          vf[dt] = *(const bf16x8*)&Vt[d * 128 + slot * 8];
        }
#pragma unroll
        for (int mt = 0; mt < 2; ++mt) {
          // B-fragment: lane (q=li, g) needs keys kk2*32 + g*8 .. +7 of this half.
          // Source tile kk2*2 + (g>>1); lanes slo / slo+16 hold keys +0..3 / +4..7.
          int a0 = __shfl((int)pk[kk2 * 2][mt][0], slo);
          int a1 = __shfl((int)pk[kk2 * 2][mt][1], slo);
          int a2 = __shfl((int)pk[kk2 * 2][mt][0], slo + 16);
          int a3 = __shfl((int)pk[kk2 * 2][mt][1], slo + 16);
          int c0 = __shfl((int)pk[kk2 * 2 + 1][mt][0], slo);
          int c1 = __shfl((int)pk[kk2 * 2 + 1][mt][1], slo);
          int c2 = __shfl((int)pk[kk2 * 2 + 1][mt][0], slo + 16);
          int c3 = __shfl((int)pk[kk2 * 2 + 1][mt][1], slo + 16);
          bool hi = (g & 2) != 0;
          uint4 bb;
          bb.x = hi ? c0 : a0;
          bb.y = hi ? c1 : a1;
          bb.z = hi ? c2 : a2;
          bb.w = hi ? c3 : a3;
          bf16x8 pf = __builtin_bit_cast(bf16x8, bb);
#pragma unroll
          for (int dt = 0; dt < 4; ++dt)
            oacc[dt][mt] =
                __builtin_amdgcn_mfma_f32_16x16x32_bf16(vf[dt], pf, oacc[dt][mt], 0, 0, 0);
        }
      }
    }
  }

  // epilogue: lane holds O^T col q=li, rows d=dt*16+g*4+r -> O[q][d] contiguous in d
#pragma unroll
  for (int mt = 0; mt < 2; ++mt) {
    float inv = 1.0f / lsum[mt];
    int row = s0 + wv * 32 + mt * 16 + li;
#pragma unroll
    for (int dt = 0; dt < 4; ++dt) {
      ushort4 w;
      w.x = f2bf(oacc[dt][mt][0] * inv);
      w.y = f2bf(oacc[dt][mt][1] * inv);
      w.z = f2bf(oacc[dt][mt][2] * inv);
      w.w = f2bf(oacc[dt][mt][3] * inv);
      *(ushort4*)(Op + (size_t)row * E + dt * 16 + g * 4) = w;
    }
  }
}

// ---------------- launch ----------------
extern "C" void kernel_launch(void* const* d_in, const int* in_sizes, int n_in,
                              void* d_out, int out_size, void* d_ws, size_t ws_size,
                              hipStream_t stream) {
  const float* q  = (const float*)d_in[0];
  const float* k  = (const float*)d_in[1];
  const float* v  = (const float*)d_in[2];
  const float* Wq = (const float*)d_in[3];
  const float* bq = (const float*)d_in[4];
  const float* Wk = (const float*)d_in[5];
  const float* bk = (const float*)d_in[6];
  const float* Wv = (const float*)d_in[7];
  const float* bv = (const float*)d_in[8];
  const float* Wo = (const float*)d_in[9];
  const float* bo = (const float*)d_in[10];

  unsigned short* Xq  = (unsigned short*)d_ws;
  unsigned short* Xk  = Xq + (size_t)MROWS * E;
  unsigned short* Xv  = Xk + (size_t)MROWS * E;
  unsigned short* Wqb = Xv + (size_t)MROWS * E;
  unsigned short* Wkb = Wqb + (size_t)E * E;
  unsigned short* Wvb = Wkb + (size_t)E * E;
  unsigned short* Wob = Wvb + (size_t)E * E;
  unsigned short* Qb  = Wob + (size_t)E * E;
  unsigned short* Kb  = Qb + (size_t)MROWS * E;
  unsigned short* Vb  = Kb + (size_t)MROWS * E;
  unsigned short* Og  = Xq; // Xq region is dead after the QKV GEMM

  CastArgs ca;
  ca.src[0] = q; ca.src[1] = k; ca.src[2] = v; ca.src[3] = nullptr;
  ca.dst[0] = Xq; ca.dst[1] = Xk; ca.dst[2] = Xv; ca.dst[3] = nullptr;
  ca.n = MROWS * E;
  cast_kernel<<<dim3(1024, 1, 3), 256, 0, stream>>>(ca);

  CastArgs cw;
  cw.src[0] = Wq; cw.src[1] = Wk; cw.src[2] = Wv; cw.src[3] = Wo;
  cw.dst[0] = Wqb; cw.dst[1] = Wkb; cw.dst[2] = Wvb; cw.dst[3] = Wob;
  cw.n = E * E;
  cast_kernel<<<dim3(256, 1, 4), 256, 0, stream>>>(cw);

  QkvArgs p;
  p.A[0] = Xq;  p.A[1] = Xk;  p.A[2] = Xv;
  p.W[0] = Wqb; p.W[1] = Wkb; p.W[2] = Wvb;
  p.bias[0] = bq; p.bias[1] = bk; p.bias[2] = bv;
  p.out[0] = Qb; p.out[1] = Kb; p.out[2] = Vb;
  p.scale[0] = 0.125f; p.scale[1] = 1.0f; p.scale[2] = 1.0f; // SCALE folded into Q
  gemm_qkv<<<dim3(64, 8, 3), 256, 0, stream>>>(p);

  flash_kernel<<<dim3(16, 64), 256, 0, stream>>>(Qb, Kb, Vb, Og);

  gemm_out_k<<<dim3(64, 8), 256, 0, stream>>>(Og, Wob, bo, (float*)d_out);
}

// Round 4
// 405.688 us; speedup vs baseline: 1.4181x; 1.0047x over previous
//
#include <hip/hip_runtime.h>

// Attention_72275709657473 — full MHA block on gfx950.
// Pipeline: cast(fp32->bf16) -> QKV proj GEMM (bf16 MFMA) -> causal flash attn -> out proj.
// Flash: TRANSPOSED formulation (S^T = K Q^T, O^T = V^T P^T; P C-layout -> PV B-frag via
// in-wave shuffles, no P LDS), with:
//   * triangle pairing: block (p,bh) owns q-tiles {p, 15-p} -> exactly 17 tile-computes
//     per block (balanced grid, 512 blocks), staged K/V shared by both q-tiles for j<=p
//   * double-buffered LDS (64KB, 2 blocks/CU) with prefetch: async16 K + V global loads
//     issued right after the single per-iter barrier; V scatter deferred to end of compute
// ws layout: Xq/Xk/Xv bf16 (3x16MB) | Wq/Wk/Wv/Wo bf16 (4x2MB) | Q/K/V bf16 (3x16MB).
// Og (attn output, bf16) reuses the Xq region. Total ~104MB.

#define E 1024
#define HEADS 16
#define HD 64
#define SEQ 2048
#define BATCH 4
#define MROWS (BATCH * SEQ) /* 8192 */

typedef __bf16 bf16x8 __attribute__((ext_vector_type(8)));
typedef __bf16 bf16x2 __attribute__((ext_vector_type(2)));
typedef float f32x4 __attribute__((ext_vector_type(4)));
typedef unsigned short ushort8v __attribute__((ext_vector_type(8)));

typedef __attribute__((address_space(1))) void gvoid;
typedef __attribute__((address_space(3))) void lvoid;

__device__ __forceinline__ void async16(const void* g, void* l) {
  __builtin_amdgcn_global_load_lds((gvoid*)g, (lvoid*)l, 16, 0, 0);
}

__device__ __forceinline__ unsigned short f2bf(float f) {
  union { float f; unsigned int u; } v;
  v.f = f;
  unsigned int r = v.u + 0x7FFFu + ((v.u >> 16) & 1u); // round-to-nearest-even
  return (unsigned short)(r >> 16);
}

__device__ __forceinline__ unsigned packbf(float a, float b) {
  bf16x2 t;
  t[0] = (__bf16)a;
  t[1] = (__bf16)b;
  return __builtin_bit_cast(unsigned, t);
}

__device__ __forceinline__ void store_out(unsigned short* p, float v) { *p = f2bf(v); }
__device__ __forceinline__ void store_out(float* p, float v) { *p = v; }

// ---------------- cast kernels ----------------
struct CastArgs {
  const float* src[4];
  unsigned short* dst[4];
  int n;
};

__global__ __launch_bounds__(256) void cast_kernel(CastArgs a) {
  const float* s = a.src[blockIdx.z];
  unsigned short* d = a.dst[blockIdx.z];
  const int n = a.n;
  const int stride = gridDim.x * blockDim.x * 4;
  for (int i = (blockIdx.x * blockDim.x + threadIdx.x) * 4; i < n; i += stride) {
    float4 v = *(const float4*)(s + i);
    ushort4 o;
    o.x = f2bf(v.x); o.y = f2bf(v.y); o.z = f2bf(v.z); o.w = f2bf(v.w);
    *(ushort4*)(d + i) = o;
  }
}

// ---------------- GEMM: C[M,N] = A[M,K] @ W[N,K]^T, epilogue (acc+bias)*scale ----------------
// 128x128 tile, BK=64, 256 threads = 4 waves in 2x2, each wave 64x64 (4x4 of 16x16x32 MFMA).
// LDS tiles row-major 128x64 bf16, XOR chunk swizzle: chunk c of row r at slot c^(r&7).
template <typename OutT>
__device__ __forceinline__ void gemm_body(const unsigned short* __restrict__ A,
                                          const unsigned short* __restrict__ W,
                                          const float* __restrict__ bias,
                                          OutT* __restrict__ out, float scale) {
  __shared__ unsigned short At[128 * 64];
  __shared__ unsigned short Wt[128 * 64];
  const int tid = threadIdx.x;
  const int lane = tid & 63;
  const int wv = tid >> 6;
  const int wm = wv & 1, wn = wv >> 1;
  const int li = lane & 15, g = lane >> 4;
  const int m0 = blockIdx.x * 128, n0 = blockIdx.y * 128;
  f32x4 acc[4][4] = {};

  for (int k0 = 0; k0 < E; k0 += 64) {
    __syncthreads();
#pragma unroll
    for (int i = 0; i < 4; ++i) {
      int c = tid + 256 * i;
      int row = c >> 3, slot = c & 7;
      int gc = slot ^ (row & 7);
      async16(A + (size_t)(m0 + row) * E + k0 + gc * 8, &At[c * 8]);
      async16(W + (size_t)(n0 + row) * E + k0 + gc * 8, &Wt[c * 8]);
    }
    asm volatile("s_waitcnt vmcnt(0)" ::: "memory");
    __syncthreads();
#pragma unroll
    for (int kk = 0; kk < 2; ++kk) {
      bf16x8 af[4], bfr[4];
#pragma unroll
      for (int mt = 0; mt < 4; ++mt) {
        int r = wm * 64 + mt * 16 + li;
        int slot = (kk * 4 + g) ^ (r & 7);
        af[mt] = *(const bf16x8*)&At[r * 64 + slot * 8];
      }
#pragma unroll
      for (int nt = 0; nt < 4; ++nt) {
        int r = wn * 64 + nt * 16 + li;
        int slot = (kk * 4 + g) ^ (r & 7);
        bfr[nt] = *(const bf16x8*)&Wt[r * 64 + slot * 8];
      }
#pragma unroll
      for (int mt = 0; mt < 4; ++mt)
#pragma unroll
        for (int nt = 0; nt < 4; ++nt)
          acc[mt][nt] =
              __builtin_amdgcn_mfma_f32_16x16x32_bf16(af[mt], bfr[nt], acc[mt][nt], 0, 0, 0);
    }
  }

#pragma unroll
  for (int nt = 0; nt < 4; ++nt) {
    int col = n0 + wn * 64 + nt * 16 + li;
    float bv = bias[col];
#pragma unroll
    for (int mt = 0; mt < 4; ++mt) {
#pragma unroll
      for (int r = 0; r < 4; ++r) {
        int row = m0 + wm * 64 + mt * 16 + g * 4 + r;
        store_out(&out[(size_t)row * E + col], (acc[mt][nt][r] + bv) * scale);
      }
    }
  }
}

struct QkvArgs {
  const unsigned short* A[3];
  const unsigned short* W[3];
  const float* bias[3];
  unsigned short* out[3];
  float scale[3];
};

__global__ __launch_bounds__(256) void gemm_qkv(QkvArgs p) {
  const int z = blockIdx.z;
  gemm_body<unsigned short>(p.A[z], p.W[z], p.bias[z], p.out[z], p.scale[z]);
}

__global__ __launch_bounds__(256) void gemm_out_k(const unsigned short* __restrict__ A,
                                                  const unsigned short* __restrict__ W,
                                                  const float* __restrict__ bias,
                                                  float* __restrict__ out) {
  gemm_body<float>(A, W, bias, out, 1.0f);
}

// ---------------- causal flash attention (transposed, paired, double-buffered) ----------------
// grid (8 pairs, 64 b*h), 256 threads = 4 waves; wave w owns rows [32w,32w+32) of BOTH
// q-tiles {p, 15-p}. Per staged 128-key tile j (0..15-p): compute hi tile always, lo tile
// when j <= p. 64-key chunks keep sacc/pk small. One barrier per iter; prefetch j+1.
__global__ __launch_bounds__(256, 2) void flash_kernel(const unsigned short* __restrict__ Qb,
                                                       const unsigned short* __restrict__ Kb,
                                                       const unsigned short* __restrict__ Vb,
                                                       unsigned short* __restrict__ Ob) {
  __shared__ unsigned short Kt[2][128 * 64];
  __shared__ unsigned short Vt[2][64 * 128];
  const int p = blockIdx.x;  // 0..7
  const int bh = blockIdx.y;
  const int b = bh >> 4, h16 = bh & 15;
  const size_t base = (size_t)b * SEQ * E + (size_t)h16 * HD;
  const unsigned short* Qp = Qb + base;
  const unsigned short* Kp = Kb + base;
  const unsigned short* Vp = Vb + base;
  unsigned short* Op = Ob + base;
  const int tid = threadIdx.x, lane = tid & 63, wv = tid >> 6;
  const int li = lane & 15, g = lane >> 4;
  const int qlo = p, qhi = 15 - p;
  const int slo = ((g & 1) << 5) | li; // source lane for P shuffles (lo half)

  // Q fragments (B-operand layout): lane holds Q[q = li][d = kk*32 + g*8 .. +7]
  bf16x8 qfL[2][2], qfH[2][2];
#pragma unroll
  for (int mt = 0; mt < 2; ++mt)
#pragma unroll
    for (int kk = 0; kk < 2; ++kk) {
      int rl = qlo * 128 + wv * 32 + mt * 16 + li;
      int rh = qhi * 128 + wv * 32 + mt * 16 + li;
      qfL[mt][kk] = *(const bf16x8*)(Qp + (size_t)rl * E + kk * 32 + g * 8);
      qfH[mt][kk] = *(const bf16x8*)(Qp + (size_t)rh * E + kk * 32 + g * 8);
    }

  f32x4 oaL[4][2] = {}, oaH[4][2] = {}; // O^T C-layout: col=q=li, row=d=g*4+r
  float miL[2] = {-1e30f, -1e30f}, lsL[2] = {0.0f, 0.0f};
  float miH[2] = {-1e30f, -1e30f}, lsH[2] = {0.0f, 0.0f};

  ushort8v vv[4]; // V prefetch registers

  auto loadV = [&](int j) {
#pragma unroll
    for (int i = 0; i < 4; ++i) {
      int c = tid + 256 * i;
      int key = c & 127, db = (c >> 7) * 8;
      vv[i] = *(const ushort8v*)(Vp + (size_t)(j * 128 + key) * E + db);
    }
  };
  auto stageK = [&](int j, int buf) {
#pragma unroll
    for (int i = 0; i < 4; ++i) {
      int c = tid + 256 * i;
      int row = c >> 3, slot = c & 7;
      int gc = slot ^ (row & 7);
      async16(Kp + (size_t)(j * 128 + row) * E + gc * 8, &Kt[buf][c * 8]);
    }
  };
  auto scatV = [&](int buf) {
#pragma unroll
    for (int i = 0; i < 4; ++i) {
      int c = tid + 256 * i;
      int key = c & 127, db = (c >> 7) * 8;
#pragma unroll
      for (int jj = 0; jj < 8; ++jj) {
        int n = db + jj;
        int slot = (key >> 3) ^ (n & 15);
        Vt[buf][n * 128 + slot * 8 + (key & 7)] = vv[i][jj];
      }
    }
  };

  auto compute = [&](const bf16x8 (&qf)[2][2], float (&mi)[2], float (&ls)[2],
                     f32x4 (&oa)[4][2], bool diag, int buf) {
#pragma unroll
    for (int h = 0; h < 2; ++h) {
      // wave-uniform skip: chunk entirely above the diagonal for this wave's rows
      if (diag && h * 64 > wv * 32 + 31) continue;

      // S^T = K Q^T for 64 keys: 4 key-tiles x 2 q-tiles
      f32x4 sacc[4][2] = {};
#pragma unroll
      for (int kk = 0; kk < 2; ++kk) {
        bf16x8 kf[4];
#pragma unroll
        for (int nt = 0; nt < 4; ++nt) {
          int key = h * 64 + nt * 16 + li;
          int slot = (kk * 4 + g) ^ (key & 7);
          kf[nt] = *(const bf16x8*)&Kt[buf][key * 64 + slot * 8];
        }
#pragma unroll
        for (int nt = 0; nt < 4; ++nt)
#pragma unroll
          for (int mt = 0; mt < 2; ++mt)
            sacc[nt][mt] =
                __builtin_amdgcn_mfma_f32_16x16x32_bf16(kf[nt], qf[mt][kk], sacc[nt][mt], 0, 0, 0);
      }

      if (diag && h * 64 + 63 > wv * 32) { // chunk overlaps diagonal: mask key > q
#pragma unroll
        for (int nt = 0; nt < 4; ++nt)
#pragma unroll
          for (int mt = 0; mt < 2; ++mt)
#pragma unroll
            for (int r = 0; r < 4; ++r) {
              int keyg = h * 64 + nt * 16 + g * 4 + r;
              int qg = wv * 32 + mt * 16 + li;
              sacc[nt][mt][r] = (keyg > qg) ? -1e30f : sacc[nt][mt][r];
            }
      }

      // online softmax per q (C-layout col): in-lane 16 keys, then shfl_xor 16/32
      float alpha[2];
#pragma unroll
      for (int mt = 0; mt < 2; ++mt) {
        float mx = sacc[0][mt][0];
#pragma unroll
        for (int nt = 0; nt < 4; ++nt)
#pragma unroll
          for (int r = 0; r < 4; ++r) mx = fmaxf(mx, sacc[nt][mt][r]);
        mx = fmaxf(mx, __shfl_xor(mx, 16));
        mx = fmaxf(mx, __shfl_xor(mx, 32));
        float mnew = fmaxf(mi[mt], mx);
        alpha[mt] = __expf(mi[mt] - mnew);
        mi[mt] = mnew;
      }

      unsigned pk[4][2][2]; // packed bf16 P^T: [key-tile][q-tile][reg-pair]
      float rs[2] = {0.0f, 0.0f};
#pragma unroll
      for (int nt = 0; nt < 4; ++nt)
#pragma unroll
        for (int mt = 0; mt < 2; ++mt) {
          float p0 = __expf(sacc[nt][mt][0] - mi[mt]);
          float p1 = __expf(sacc[nt][mt][1] - mi[mt]);
          float p2 = __expf(sacc[nt][mt][2] - mi[mt]);
          float p3 = __expf(sacc[nt][mt][3] - mi[mt]);
          rs[mt] += (p0 + p1) + (p2 + p3);
          pk[nt][mt][0] = packbf(p0, p1);
          pk[nt][mt][1] = packbf(p2, p3);
        }
#pragma unroll
      for (int mt = 0; mt < 2; ++mt) {
        float s = rs[mt];
        s += __shfl_xor(s, 16);
        s += __shfl_xor(s, 32);
        ls[mt] = ls[mt] * alpha[mt] + s;
#pragma unroll
        for (int dt = 0; dt < 4; ++dt) oa[dt][mt] *= alpha[mt];
      }

      // O^T += V^T P^T over 2 chunks of 32 keys
#pragma unroll
      for (int kk2 = 0; kk2 < 2; ++kk2) {
        const int kc = h * 2 + kk2; // 32-key chunk index within the 128-key tile
        bf16x8 vf[4];
#pragma unroll
        for (int dt = 0; dt < 4; ++dt) {
          int d = dt * 16 + li;
          int slot = (kc * 4 + g) ^ (d & 15);
          vf[dt] = *(const bf16x8*)&Vt[buf][d * 128 + slot * 8];
        }
#pragma unroll
        for (int mt = 0; mt < 2; ++mt) {
          // B-fragment: lane (q=li, g) needs keys kk2*32 + g*8 .. +7 of this half.
          // Source tile kk2*2 + (g>>1); lanes slo / slo+16 hold keys +0..3 / +4..7.
          int a0 = __shfl((int)pk[kk2 * 2][mt][0], slo);
          int a1 = __shfl((int)pk[kk2 * 2][mt][1], slo);
          int a2 = __shfl((int)pk[kk2 * 2][mt][0], slo + 16);
          int a3 = __shfl((int)pk[kk2 * 2][mt][1], slo + 16);
          int c0 = __shfl((int)pk[kk2 * 2 + 1][mt][0], slo);
          int c1 = __shfl((int)pk[kk2 * 2 + 1][mt][1], slo);
          int c2 = __shfl((int)pk[kk2 * 2 + 1][mt][0], slo + 16);
          int c3 = __shfl((int)pk[kk2 * 2 + 1][mt][1], slo + 16);
          bool hi = (g & 2) != 0;
          uint4 bb;
          bb.x = hi ? c0 : a0;
          bb.y = hi ? c1 : a1;
          bb.z = hi ? c2 : a2;
          bb.w = hi ? c3 : a3;
          bf16x8 pf = __builtin_bit_cast(bf16x8, bb);
#pragma unroll
          for (int dt = 0; dt < 4; ++dt)
            oa[dt][mt] =
                __builtin_amdgcn_mfma_f32_16x16x32_bf16(vf[dt], pf, oa[dt][mt], 0, 0, 0);
        }
      }
    }
  };

  // prologue: stage tile 0 into buf 0
  loadV(0);
  stageK(0, 0);
  scatV(0);

  for (int j = 0; j <= qhi; ++j) {
    const int buf = j & 1;
    asm volatile("s_waitcnt vmcnt(0)" ::: "memory"); // K(j) async + any V loads drained
    __syncthreads();                                  // staging of tile j visible to all
    if (j < qhi) {
      loadV(j + 1);          // V global loads in flight across the compute phase
      stageK(j + 1, buf ^ 1); // async16 into the retired buffer
    }
    compute(qfH, miH, lsH, oaH, j == qhi, buf);
    if (j <= qlo) compute(qfL, miL, lsL, oaL, j == qlo, buf);
    if (j < qhi) scatV(buf ^ 1); // transpose-scatter V(j+1); visible after next barrier
  }

  // epilogue: lane holds O^T col q=li, rows d=dt*16+g*4+r -> O[q][d] contiguous in d
#pragma unroll
  for (int t = 0; t < 2; ++t) {
    const int qt = t ? qhi : qlo;
    f32x4(&oa)[4][2] = t ? oaH : oaL;
    float* ls = t ? lsH : lsL;
#pragma unroll
    for (int mt = 0; mt < 2; ++mt) {
      float inv = 1.0f / ls[mt];
      int row = qt * 128 + wv * 32 + mt * 16 + li;
#pragma unroll
      for (int dt = 0; dt < 4; ++dt) {
        ushort4 w;
        w.x = f2bf(oa[dt][mt][0] * inv);
        w.y = f2bf(oa[dt][mt][1] * inv);
        w.z = f2bf(oa[dt][mt][2] * inv);
        w.w = f2bf(oa[dt][mt][3] * inv);
        *(ushort4*)(Op + (size_t)row * E + dt * 16 + g * 4) = w;
      }
    }
  }
}

// ---------------- launch ----------------
extern "C" void kernel_launch(void* const* d_in, const int* in_sizes, int n_in,
                              void* d_out, int out_size, void* d_ws, size_t ws_size,
                              hipStream_t stream) {
  const float* q  = (const float*)d_in[0];
  const float* k  = (const float*)d_in[1];
  const float* v  = (const float*)d_in[2];
  const float* Wq = (const float*)d_in[3];
  const float* bq = (const float*)d_in[4];
  const float* Wk = (const float*)d_in[5];
  const float* bk = (const float*)d_in[6];
  const float* Wv = (const float*)d_in[7];
  const float* bv = (const float*)d_in[8];
  const float* Wo = (const float*)d_in[9];
  const float* bo = (const float*)d_in[10];

  unsigned short* Xq  = (unsigned short*)d_ws;
  unsigned short* Xk  = Xq + (size_t)MROWS * E;
  unsigned short* Xv  = Xk + (size_t)MROWS * E;
  unsigned short* Wqb = Xv + (size_t)MROWS * E;
  unsigned short* Wkb = Wqb + (size_t)E * E;
  unsigned short* Wvb = Wkb + (size_t)E * E;
  unsigned short* Wob = Wvb + (size_t)E * E;
  unsigned short* Qb  = Wob + (size_t)E * E;
  unsigned short* Kb  = Qb + (size_t)MROWS * E;
  unsigned short* Vb  = Kb + (size_t)MROWS * E;
  unsigned short* Og  = Xq; // Xq region is dead after the QKV GEMM

  CastArgs ca;
  ca.src[0] = q; ca.src[1] = k; ca.src[2] = v; ca.src[3] = nullptr;
  ca.dst[0] = Xq; ca.dst[1] = Xk; ca.dst[2] = Xv; ca.dst[3] = nullptr;
  ca.n = MROWS * E;
  cast_kernel<<<dim3(1024, 1, 3), 256, 0, stream>>>(ca);

  CastArgs cw;
  cw.src[0] = Wq; cw.src[1] = Wk; cw.src[2] = Wv; cw.src[3] = Wo;
  cw.dst[0] = Wqb; cw.dst[1] = Wkb; cw.dst[2] = Wvb; cw.dst[3] = Wob;
  cw.n = E * E;
  cast_kernel<<<dim3(256, 1, 4), 256, 0, stream>>>(cw);

  QkvArgs p;
  p.A[0] = Xq;  p.A[1] = Xk;  p.A[2] = Xv;
  p.W[0] = Wqb; p.W[1] = Wkb; p.W[2] = Wvb;
  p.bias[0] = bq; p.bias[1] = bk; p.bias[2] = bv;
  p.out[0] = Qb; p.out[1] = Kb; p.out[2] = Vb;
  p.scale[0] = 0.125f; p.scale[1] = 1.0f; p.scale[2] = 1.0f; // SCALE folded into Q
  gemm_qkv<<<dim3(64, 8, 3), 256, 0, stream>>>(p);

  flash_kernel<<<dim3(8, 64), 256, 0, stream>>>(Qb, Kb, Vb, Og);

  gemm_out_k<<<dim3(64, 8), 256, 0, stream>>>(Og, Wob, bo, (float*)d_out);
}